// Round 6
// baseline (1487.398 us; speedup 1.0000x reference)
//
#include <hip/hip_runtime.h>

// EdgeCNN (DynamicEdgeConv): N=20000, F=64, H=128, K=6 (incl self). All f32.
// ROUND-6: MFMA distances are a FILTER (hi-bf16 only, error ~±0.1), exact f32
// re-rank (rescue) picks the final top-6. Round-5's split-bf16 (~2e-4 err) hit
// rank-6/7 near-ties (~8 rows) -> absmax 0.26. The rescue restores the f32
// ranking that passed in round 3. 12 candidates/row/chunk (two 8-lane-half
// top-6 lists, disjoint j residues); filter-miss probability ~1e-7 total.

#define N_NODES 20000
#define FDIM 64
#define KNN 6
#define HID 128
#define TILE_J 64
#define N_PAD 20480
#define R_PAD 20032          // 313 * 64
#define LDS_STRIDE 72        // ushorts per row (144 B)
#define MAX_CHUNKS 4

typedef __bf16 v8bf __attribute__((ext_vector_type(8)));
typedef float f32x4 __attribute__((ext_vector_type(4)));
union FragU { uint4 u; v8bf v; };

__device__ __forceinline__ unsigned short f2bf_rne(float f) {
  union { float f; unsigned int u; } c; c.f = f;
  return (unsigned short)((c.u + 0x7fffu + ((c.u >> 16) & 1u)) >> 16);
}

// Branchless sorted-ascending 6-slot insert, strict '<' (per-lane ascending-j
// candidate order => lowest-j wins ties).
__device__ __forceinline__ void ins6(float d, int j, float (&bd)[6], int (&bj)[6]) {
  if (d < bd[5]) {
    const bool c0 = d < bd[0], c1 = d < bd[1], c2 = d < bd[2];
    const bool c3 = d < bd[3], c4 = d < bd[4];
    bd[5] = c4 ? bd[4] : d;              bj[5] = c4 ? bj[4] : j;
    bd[4] = c4 ? (c3 ? bd[3] : d) : bd[4]; bj[4] = c4 ? (c3 ? bj[3] : j) : bj[4];
    bd[3] = c3 ? (c2 ? bd[2] : d) : bd[3]; bj[3] = c3 ? (c2 ? bj[2] : j) : bj[3];
    bd[2] = c2 ? (c1 ? bd[1] : d) : bd[2]; bj[2] = c2 ? (c1 ? bj[1] : j) : bj[2];
    bd[1] = c1 ? (c0 ? bd[0] : d) : bd[1]; bj[1] = c1 ? (c0 ? bj[0] : j) : bj[1];
    bd[0] = c0 ? d : bd[0];              bj[0] = c0 ? j : bj[0];
  }
}

// Lexicographic (d, then j) insert for unordered candidate streams.
__device__ __forceinline__ void ins6_lex(float d, int j, float (&bd)[6], int (&bj)[6]) {
  bool c[6];
#pragma unroll
  for (int k = 0; k < 6; ++k)
    c[k] = (d < bd[k]) || (d == bd[k] && j < bj[k]);
#pragma unroll
  for (int k = 5; k >= 1; --k) {
    bd[k] = c[k] ? (c[k - 1] ? bd[k - 1] : d) : bd[k];
    bj[k] = c[k] ? (c[k - 1] ? bj[k - 1] : j) : bj[k];
  }
  bd[0] = c[0] ? d : bd[0];
  bj[0] = c[0] ? j : bj[0];
}

#define INSERT_CAND(dv, jv) ins6((dv), (jv), bd, bj)

__global__ void sq_kernel(const float* __restrict__ x, float* __restrict__ sq) {
  const int i = blockIdx.x * blockDim.x + threadIdx.x;
  if (i >= N_NODES) return;
  const float4* r4 = (const float4*)(x + (size_t)i * FDIM);
  float s = 0.f;
#pragma unroll
  for (int q = 0; q < 16; ++q) {
    const float4 a = r4[q];
    s = fmaf(a.x, a.x, s); s = fmaf(a.y, a.y, s);
    s = fmaf(a.z, a.z, s); s = fmaf(a.w, a.w, s);
  }
  sq[i] = s;
}

// x (f32) -> xhi (bf16 rne), rows >= N zero-padded to R_PAD.
__global__ void split_kernel(const float* __restrict__ x,
                             unsigned short* __restrict__ xhi) {
  const int t = blockIdx.x * blockDim.x + threadIdx.x;  // one float4 per thread
  if (t >= R_PAD * (FDIM / 4)) return;
  const int row = t >> 4;
  const int q = t & 15;
  float4 v = make_float4(0.f, 0.f, 0.f, 0.f);
  if (row < N_NODES) v = *(const float4*)(x + (size_t)row * FDIM + q * 4);
  ushort4 h;
  h.x = f2bf_rne(v.x); h.y = f2bf_rne(v.y);
  h.z = f2bf_rne(v.z); h.w = f2bf_rne(v.w);
  *(ushort4*)(xhi + (size_t)row * FDIM + q * 4) = h;
}

// Approximate distances via hi-bf16 MFMA; emit 12 candidate j's per row/chunk.
__global__ __launch_bounds__(256, 2) void knn_mfma_kernel(
    const unsigned short* __restrict__ xhi, const float* __restrict__ sq,
    int* __restrict__ cand_j, int jchunk, int nchunks) {
  __shared__ __align__(16) unsigned short sh_hi[TILE_J * LDS_STRIDE];
  __shared__ float sqs[TILE_J];
  const int tid = threadIdx.x;
  const int lane = tid & 63;
  const int wave = tid >> 6;
  const int c = lane & 15;        // column within 16x16 tile
  const int quad = lane >> 4;     // k-group (frags) / row-group (C)
  const int jc = blockIdx.y;
  const int rowbase = blockIdx.x * 64 + wave * 16;

  // A-frags: lane holds A[m=c][k=quad*8+jj], two K=32 steps.
  v8bf ahi0, ahi1;
  {
    const size_t ar = (size_t)(rowbase + c) * FDIM + quad * 8;
    FragU f;
    f.u = *(const uint4*)(xhi + ar);      ahi0 = f.v;
    f.u = *(const uint4*)(xhi + ar + 32); ahi1 = f.v;
  }
  float sqi[4];
#pragma unroll
  for (int r = 0; r < 4; ++r) sqi[r] = sq[rowbase + quad * 4 + r];

  float bdl[4][6];
  int bjl[4][6];
#pragma unroll
  for (int r = 0; r < 4; ++r)
#pragma unroll
    for (int k = 0; k < 6; ++k) { bdl[r][k] = __builtin_inff(); bjl[r][k] = 0; }

  const int jcb = jc * jchunk;
  for (int jt = 0; jt < jchunk; jt += TILE_J) {
    const int jbase = jcb + jt;
    __syncthreads();
    {
      const int jr = tid >> 2, sg = tid & 3;
      const int j = jbase + jr;
      const int lb = jr * LDS_STRIDE + sg * 16;
      uint4 h0, h1;
      if (j < R_PAD) {
        const size_t g = (size_t)j * FDIM + sg * 16;
        h0 = *(const uint4*)(xhi + g); h1 = *(const uint4*)(xhi + g + 8);
      } else {
        h0 = h1 = make_uint4(0u, 0u, 0u, 0u);
      }
      *(uint4*)(sh_hi + lb) = h0; *(uint4*)(sh_hi + lb + 8) = h1;
      if (tid < TILE_J) {
        const int j2 = jbase + tid;
        sqs[tid] = (j2 < N_NODES) ? sq[j2] : 0.f;
      }
    }
    __syncthreads();

#pragma unroll
    for (int n0 = 0; n0 < TILE_J; n0 += 16) {
      const int bro = (n0 + c) * LDS_STRIDE + quad * 8;
      FragU f;
      v8bf bh0, bh1;
      f.u = *(const uint4*)(sh_hi + bro);      bh0 = f.v;
      f.u = *(const uint4*)(sh_hi + bro + 32); bh1 = f.v;
      f32x4 acc = {0.f, 0.f, 0.f, 0.f};
      acc = __builtin_amdgcn_mfma_f32_16x16x32_bf16(ahi0, bh0, acc, 0, 0, 0);
      acc = __builtin_amdgcn_mfma_f32_16x16x32_bf16(ahi1, bh1, acc, 0, 0, 0);
      const int j = jbase + n0 + c;
      const float sqj = sqs[n0 + c];
      const bool jok = j < N_NODES;
#pragma unroll
      for (int r = 0; r < 4; ++r) {
        float d = fmaf(-2.f, acc[r], sqi[r] + sqj);
        d = jok ? d : __builtin_inff();
        ins6(d, j, bdl[r], bjl[r]);  // per-lane j strictly ascending
      }
    }
  }

  // Merge masks {1,2,4}: each 8-lane half of a row group folds to a top-6.
#pragma unroll
  for (int mask = 1; mask <= 4; mask <<= 1) {
#pragma unroll
    for (int r = 0; r < 4; ++r) {
      float od[6]; int oj[6];
#pragma unroll
      for (int k = 0; k < 6; ++k) {
        od[k] = __shfl_xor(bdl[r][k], mask, 64);
        oj[k] = __shfl_xor(bjl[r][k], mask, 64);
      }
#pragma unroll
      for (int k = 0; k < 6; ++k) ins6_lex(od[k], oj[k], bdl[r], bjl[r]);
    }
  }

  if ((c & 7) == 0) {  // lanes c==0 and c==8: one writer per half
    const int half = c >> 3;
#pragma unroll
    for (int r = 0; r < 4; ++r) {
      const int i = rowbase + quad * 4 + r;
      if (i < N_NODES) {
#pragma unroll
        for (int k = 0; k < KNN; ++k) {
          const size_t off = (((size_t)jc * 2 + half) * KNN + k) * N_PAD + i;
          cand_j[off] = bjl[r][k];
        }
      }
    }
  }
}

// Exact f32 re-rank of the nc*12 candidates (same FMA-chain order as the
// round-3 kernel that passed) -> final top-6 sets.
__global__ void knn_rescue_kernel(const float* __restrict__ x,
                                  const float* __restrict__ sq,
                                  const int* __restrict__ cand_j,
                                  int* __restrict__ knn_idx, int nsets) {
  const int i = blockIdx.x * blockDim.x + threadIdx.x;
  if (i >= N_NODES) return;
  const float4* xi4 = (const float4*)(x + (size_t)i * FDIM);
  const float sqi = sq[i];
  float bd[6]; int bj[6];
#pragma unroll
  for (int k = 0; k < 6; ++k) { bd[k] = __builtin_inff(); bj[k] = 0; }
  for (int s = 0; s < nsets; ++s) {
#pragma unroll
    for (int k = 0; k < KNN; ++k) {
      const int j = cand_j[((size_t)s * KNN + k) * N_PAD + i];
      const float4* xj4 = (const float4*)(x + (size_t)j * FDIM);
      float dot = 0.f;
#pragma unroll
      for (int q = 0; q < 16; ++q) {
        const float4 a = xi4[q];
        const float4 b = xj4[q];
        dot = fmaf(a.x, b.x, dot);
        dot = fmaf(a.y, b.y, dot);
        dot = fmaf(a.z, b.z, dot);
        dot = fmaf(a.w, b.w, dot);
      }
      const float d = fmaf(-2.f, dot, sqi + sq[j]);
      ins6_lex(d, j, bd, bj);  // candidates distinct by construction
    }
  }
#pragma unroll
  for (int k = 0; k < KNN; ++k) knn_idx[(size_t)i * KNN + k] = bj[k];
}

// ---- Fallback VALU kernel (round-3, proven): used only if ws is too small ----
__global__ __launch_bounds__(256) void knn_partial_kernel(
    const float* __restrict__ x, const float* __restrict__ sq,
    float* __restrict__ cand_d, int* __restrict__ cand_j,
    int* __restrict__ knn_idx, int jchunk, int nchunks) {
  __shared__ __align__(16) float xs[TILE_J][FDIM + 4];
  __shared__ float sqs[TILE_J];
  const int tid = threadIdx.x;
  const int i = blockIdx.x * 256 + tid;
  const bool valid = i < N_NODES;
  const int jc = blockIdx.y;
  float xi[FDIM];
  float sqi = 0.f;
  if (valid) {
    const float4* r4 = (const float4*)(x + (size_t)i * FDIM);
#pragma unroll
    for (int q = 0; q < 16; ++q) {
      const float4 a = r4[q];
      xi[q * 4 + 0] = a.x; xi[q * 4 + 1] = a.y;
      xi[q * 4 + 2] = a.z; xi[q * 4 + 3] = a.w;
    }
    sqi = sq[i];
  } else {
#pragma unroll
    for (int f = 0; f < FDIM; ++f) xi[f] = 0.f;
  }
  float bd[6]; int bj[6];
#pragma unroll
  for (int k = 0; k < 6; ++k) { bd[k] = __builtin_inff(); bj[k] = 0; }
  const int jcbase = jc * jchunk;
  for (int t0 = 0; t0 < jchunk; t0 += TILE_J) {
    const int jt = jcbase + t0;
    __syncthreads();
    {
      const int jj = tid >> 2;
      const int f0 = (tid & 3) * 16;
      const int j = jt + jj;
      float4* dst = (float4*)&xs[jj][f0];
      if (j < N_NODES) {
        const float4* src = (const float4*)(x + (size_t)j * FDIM + f0);
        dst[0] = src[0]; dst[1] = src[1]; dst[2] = src[2]; dst[3] = src[3];
      } else {
        const float4 z = make_float4(0.f, 0.f, 0.f, 0.f);
        dst[0] = z; dst[1] = z; dst[2] = z; dst[3] = z;
      }
      if (tid < TILE_J) {
        const int j2 = jt + tid;
        sqs[tid] = (j2 < N_NODES) ? sq[j2] : 0.f;
      }
    }
    __syncthreads();
    const int rem = N_NODES - jt;
    const int jmax = rem < TILE_J ? rem : TILE_J;
    for (int jj = 0; jj < jmax; ++jj) {
      const float4* xr4 = (const float4*)&xs[jj][0];
      float dot = 0.f;
#pragma unroll
      for (int q = 0; q < 16; ++q) {
        const float4 v = xr4[q];
        dot = fmaf(xi[q * 4 + 0], v.x, dot);
        dot = fmaf(xi[q * 4 + 1], v.y, dot);
        dot = fmaf(xi[q * 4 + 2], v.z, dot);
        dot = fmaf(xi[q * 4 + 3], v.w, dot);
      }
      const float d = fmaf(-2.f, dot, sqi + sqs[jj]);
      INSERT_CAND(d, jt + jj);
    }
  }
  if (valid) {
    if (nchunks == 1) {
#pragma unroll
      for (int k = 0; k < KNN; ++k) knn_idx[(size_t)i * KNN + k] = bj[k];
    } else {
#pragma unroll
      for (int k = 0; k < KNN; ++k) {
        const size_t off = ((size_t)jc * KNN + k) * N_PAD + i;
        cand_d[off] = bd[k];
        cand_j[off] = bj[k];
      }
    }
  }
}

__global__ void knn_merge_kernel(const float* __restrict__ cand_d,
                                 const int* __restrict__ cand_j,
                                 int* __restrict__ knn_idx, int nchunks) {
  const int i = blockIdx.x * blockDim.x + threadIdx.x;
  if (i >= N_NODES) return;
  float bd[6]; int bj[6];
#pragma unroll
  for (int k = 0; k < 6; ++k) { bd[k] = __builtin_inff(); bj[k] = 0; }
  for (int jc = 0; jc < nchunks; ++jc) {
#pragma unroll
    for (int k = 0; k < KNN; ++k) {
      const size_t off = ((size_t)jc * KNN + k) * N_PAD + i;
      INSERT_CAND(cand_d[off], cand_j[off]);
    }
  }
#pragma unroll
  for (int k = 0; k < KNN; ++k) knn_idx[(size_t)i * KNN + k] = bj[k];
}

__global__ __launch_bounds__(HID) void mlp_kernel(
    const float* __restrict__ x, const int* __restrict__ knn_idx,
    const float* __restrict__ W1, const float* __restrict__ b1,
    const float* __restrict__ W2, const float* __restrict__ b2,
    float* __restrict__ out) {
  __shared__ float xi_s[FDIM];
  __shared__ float xd_s[KNN][FDIM];
  __shared__ float h1_s[KNN][HID];
  __shared__ int nb[KNN];
  const int i = blockIdx.x;
  const int t = threadIdx.x;
  if (t < KNN) nb[t] = knn_idx[(size_t)i * KNN + t];
  if (t < FDIM) xi_s[t] = x[(size_t)i * FDIM + t];
  __syncthreads();
  for (int e = t; e < KNN * FDIM; e += HID) {
    const int k = e >> 6;
    const int f = e & 63;
    xd_s[k][f] = x[(size_t)nb[k] * FDIM + f] - xi_s[f];
  }
  __syncthreads();
  float s0 = b1[t];
  for (int f = 0; f < FDIM; ++f) s0 = fmaf(xi_s[f], W1[f * HID + t], s0);
  float acc[KNN];
#pragma unroll
  for (int k = 0; k < KNN; ++k) acc[k] = s0;
  for (int f = 0; f < FDIM; ++f) {
    const float w = W1[(FDIM + f) * HID + t];
#pragma unroll
    for (int k = 0; k < KNN; ++k) acc[k] = fmaf(xd_s[k][f], w, acc[k]);
  }
#pragma unroll
  for (int k = 0; k < KNN; ++k) h1_s[k][t] = fmaxf(acc[k], 0.f);
  __syncthreads();
  float acc2[KNN];
  const float bb = b2[t];
#pragma unroll
  for (int k = 0; k < KNN; ++k) acc2[k] = bb;
  for (int h = 0; h < HID; ++h) {
    const float w = W2[h * HID + t];
#pragma unroll
    for (int k = 0; k < KNN; ++k) acc2[k] = fmaf(h1_s[k][h], w, acc2[k]);
  }
  float m = acc2[0];
#pragma unroll
  for (int k = 1; k < KNN; ++k) m = fmaxf(m, acc2[k]);
  out[(size_t)i * HID + t] = m;
}

extern "C" void kernel_launch(void* const* d_in, const int* in_sizes, int n_in,
                              void* d_out, int out_size, void* d_ws, size_t ws_size,
                              hipStream_t stream) {
  const float* x  = (const float*)d_in[0];
  const float* W1 = (const float*)d_in[2];
  const float* b1 = (const float*)d_in[3];
  const float* W2 = (const float*)d_in[4];
  const float* b2 = (const float*)d_in[5];
  float* out = (float*)d_out;

  // ws: [sq N_PAD f32][knn N*K i32] | [xhi R_PAD*64 bf16] | [cand_j nc*12*N_PAD]
  const size_t BASE = 0x90000;                        // 589,824
  const size_t XHI = (size_t)R_PAD * FDIM * 2;        // 2,564,096
  const size_t PER_CHUNK_J = (size_t)12 * N_PAD * 4;  // 983,040

  char* ws = (char*)d_ws;
  float* sq = (float*)ws;
  int* knn = (int*)(ws + (size_t)N_PAD * 4);

  sq_kernel<<<dim3((N_NODES + 255) / 256), dim3(256), 0, stream>>>(x, sq);

  const bool use_mfma = ws_size >= BASE + XHI + PER_CHUNK_J;
  if (use_mfma) {
    unsigned short* xhi = (unsigned short*)(ws + BASE);
    int* cand_j = (int*)(ws + BASE + XHI);
    size_t fit = (ws_size - BASE - XHI) / PER_CHUNK_J;
    int nc = fit < (size_t)MAX_CHUNKS ? (int)fit : MAX_CHUNKS;
    if (nc < 1) nc = 1;
    const int jchunk =
        ((N_NODES + nc - 1) / nc + TILE_J - 1) / TILE_J * TILE_J;

    split_kernel<<<dim3((R_PAD * 16 + 255) / 256), dim3(256), 0, stream>>>(
        x, xhi);
    dim3 g(R_PAD / 64, nc);
    knn_mfma_kernel<<<g, dim3(256), 0, stream>>>(xhi, sq, cand_j, jchunk, nc);
    knn_rescue_kernel<<<dim3((N_NODES + 255) / 256), dim3(256), 0, stream>>>(
        x, sq, cand_j, knn, nc * 2);
  } else {
    float* cand_d = (float*)(ws + BASE);
    const size_t PER_CHUNK = (size_t)KNN * N_PAD * 8;
    size_t fit = ws_size > BASE ? (ws_size - BASE) / PER_CHUNK : 0;
    int nc = fit < 4 ? (int)fit : 4;
    if (nc < 1) nc = 1;
    int* cand_j = (int*)(ws + BASE + (size_t)nc * KNN * N_PAD * 4);
    const int jchunk =
        ((N_NODES + nc - 1) / nc + TILE_J - 1) / TILE_J * TILE_J;
    dim3 g((N_NODES + 255) / 256, nc);
    knn_partial_kernel<<<g, dim3(256), 0, stream>>>(x, sq, cand_d, cand_j, knn,
                                                    jchunk, nc);
    if (nc > 1)
      knn_merge_kernel<<<dim3((N_NODES + 255) / 256), dim3(256), 0, stream>>>(
          cand_d, cand_j, knn, nc);
  }
  mlp_kernel<<<dim3(N_NODES), dim3(HID), 0, stream>>>(x, knn, W1, b1, W2, b2,
                                                      out);
}